// Round 2
// baseline (156.220 us; speedup 1.0000x reference)
//
#include <hip/hip_runtime.h>
#include <cstddef>

namespace {
constexpr int B = 4, C = 64, H = 256, W = 256;
constexpr int HW = H * W;      // 65536
constexpr int CHW = C * HW;    // 4194304
constexpr int TH = 32;         // strip height for fused blur (38 KB LDS -> 4 blocks/CU)
constexpr float SMIN = 0.6f, SMAX = 1.2f;
}

__device__ __forceinline__ float4 ld4(const float* p) {
  return *(const float4*)p;
}
__device__ __forceinline__ void st4(float* p, float a, float b, float c, float d) {
  float4 v; v.x = a; v.y = b; v.z = c; v.w = d; *(float4*)p = v;
}

// edge': block = (b, 4-row band), ALL 64 channels (16 per wave, unroll-4 for
// ILP: ~24 loads in flight covers HBM latency at 1 block/CU occupancy).
// XCD swizzle: xcd = blockIdx%8 owns rows [xcd*32, xcd*32+32) so band halo
// rows hit the local L2. Emits final scaled edge rows directly (no P planes,
// no combine kernel) plus a non-atomic per-band {min,max} pair into mmp.
__global__ __launch_bounds__(256) void edge_kernel(
    const float* __restrict__ x, float* __restrict__ edge,
    float* __restrict__ mmp) {
  __shared__ float part[4][4][64][4];   // [wave][row][lane][px]
  __shared__ float rmn[4], rmx[4];
  const int xcd = blockIdx.x & 7;
  const int slot = blockIdx.x >> 3;          // 0..31
  const int hbb = slot & 7;                  // band within the XCD's 32 rows
  const int b = slot >> 3;                   // 0..3
  const int h0 = xcd * 32 + hbb * 4;
  const int lane = threadIdx.x & 63, wv = threadIdx.x >> 6;
  const float* base = x + (size_t)b * CHW + (size_t)(wv * 16) * HW + 4 * lane;
  float acc[4][4] = {};
  #pragma unroll 4
  for (int cc = 0; cc < 16; ++cc) {
    const float* p = base + (size_t)cc * HW;
    float4 R[6];
    #pragma unroll
    for (int i = 0; i < 6; ++i) {
      const int gh = h0 - 1 + i;
      R[i] = (gh >= 0 && gh < H) ? ld4(p + (size_t)gh * W)
                                 : float4{0.f, 0.f, 0.f, 0.f};
    }
    float Lh[6], Rh[6];
    #pragma unroll
    for (int i = 0; i < 6; ++i) {
      Lh[i] = __shfl_up(R[i].w, 1);
      Rh[i] = __shfl_down(R[i].x, 1);
    }
    if (lane == 0) {
      #pragma unroll
      for (int i = 0; i < 6; ++i) Lh[i] = 0.f;
    }
    if (lane == 63) {
      #pragma unroll
      for (int i = 0; i < 6; ++i) Rh[i] = 0.f;
    }
    #pragma unroll
    for (int r = 0; r < 4; ++r) {
      const float ra[6] = {Lh[r],     R[r].x,     R[r].y,     R[r].z,     R[r].w,     Rh[r]};
      const float rb[6] = {Lh[r + 1], R[r + 1].x, R[r + 1].y, R[r + 1].z, R[r + 1].w, Rh[r + 1]};
      const float rc[6] = {Lh[r + 2], R[r + 2].x, R[r + 2].y, R[r + 2].z, R[r + 2].w, Rh[r + 2]};
      #pragma unroll
      for (int j = 0; j < 4; ++j) {
        float gx = (ra[j + 2] - ra[j]) + 2.f * (rb[j + 2] - rb[j]) + (rc[j + 2] - rc[j]);
        float gy = (rc[j] - ra[j]) + 2.f * (rc[j + 1] - ra[j + 1]) + (rc[j + 2] - ra[j + 2]);
        acc[r][j] = fmaf(gx, gx, acc[r][j]);
        acc[r][j] = fmaf(gy, gy, acc[r][j]);
      }
    }
  }
  #pragma unroll
  for (int r = 0; r < 4; ++r)
    #pragma unroll
    for (int j = 0; j < 4; ++j) part[wv][r][lane][j] = acc[r][j];
  __syncthreads();
  // Wave wv combines + writes row wv (scaled by 1/C), then block min/max.
  const int r = wv;
  float s[4];
  #pragma unroll
  for (int j = 0; j < 4; ++j)
    s[j] = (part[0][r][lane][j] + part[1][r][lane][j] +
            part[2][r][lane][j] + part[3][r][lane][j]) * (1.f / 64.f);
  st4(edge + (size_t)b * HW + (size_t)(h0 + r) * W + 4 * lane,
      s[0], s[1], s[2], s[3]);
  float mn = fminf(fminf(s[0], s[1]), fminf(s[2], s[3]));
  float mx = fmaxf(fmaxf(s[0], s[1]), fmaxf(s[2], s[3]));
  #pragma unroll
  for (int o = 32; o > 0; o >>= 1) {
    mn = fminf(mn, __shfl_down(mn, o, 64));
    mx = fmaxf(mx, __shfl_down(mx, o, 64));
  }
  if (lane == 0) { rmn[wv] = mn; rmx[wv] = mx; }
  __syncthreads();
  if (threadIdx.x == 0) {
    mn = fminf(fminf(rmn[0], rmn[1]), fminf(rmn[2], rmn[3]));
    mx = fmaxf(fmaxf(rmx[0], rmx[1]), fmaxf(rmx[2], rmx[3]));
    const int band = xcd * 8 + hbb;            // 0..63 within batch b
    mmp[2 * (b * 64 + band)] = mn;
    mmp[2 * (b * 64 + band) + 1] = mx;
  }
}

// Per-pixel gaussian weight from the (scaled) edge value. __fdividef /
// __expf: rel err ~2^-21, negligible vs the bf16-level compare tolerance.
__device__ __forceinline__ void wt_px(float e, float emin, float inv_den,
                                      float& e1, float& iv) {
  float en = (e - emin) * inv_den;
  float sg = SMIN + (SMAX - SMIN) * en;
  float a = __fdividef(1.0f, 2.0f * sg * sg);
  e1 = __expf(-a);
  float t2 = e1 * e1, e4 = t2 * t2, e9 = e4 * e4 * e1;
  iv = __fdividef(1.0f, 1.f + 2.f * (e1 + e4 + e9));
}

// Symmetric 7-tap blur: w3 + e1*(w2+w4) + e4*(w1+w5) + e9*(w0+w6), then *iv.
__device__ __forceinline__ float blur7(const float* w, float e1, float iv) {
  float t2 = e1 * e1, e4 = t2 * t2, e9 = e4 * e4 * e1;
  float u = w[3];
  u = fmaf(e1, w[2] + w[4], u);
  u = fmaf(e4, w[1] + w[5], u);
  u = fmaf(e9, w[0] + w[6], u);
  return u * iv;
}

// Fused h+v blur, weights computed inline from edge + mmp (weights_kernel
// absorbed). Block per (b, c, 32-row strip); stage TH+6 hblurred rows in LDS,
// one barrier, vblur with rolling 7-row register window. Every wave
// butterfly-reduces the 128-value mmp[b] slice (L2-hot, no barrier needed).
__global__ __launch_bounds__(256) void fusedblur_kernel(
    const float* __restrict__ x, const float* __restrict__ edge,
    const float* __restrict__ mmp, float* __restrict__ out) {
  __shared__ float hb[TH + 6][W];
  const int xcd = blockIdx.x & 7;
  const int slot = blockIdx.x >> 3;              // 0..255
  const int s = slot & 7;                        // strip (H/TH == 8)
  const int bc = xcd * 32 + (slot >> 3);         // b*C + c
  const int b = bc >> 6;
  const int h0 = s * TH;
  const int lane = threadIdx.x & 63, wv = threadIdx.x >> 6;

  // Per-wave reduction of mmp[b][0..63][{mn,mx}] -> emin, inv_den.
  float2 mv = *(const float2*)&mmp[2 * (b * 64 + lane)];
  float mn = mv.x, mx = mv.y;
  #pragma unroll
  for (int o = 1; o < 64; o <<= 1) {
    mn = fminf(mn, __shfl_xor(mn, o, 64));
    mx = fmaxf(mx, __shfl_xor(mx, o, 64));
  }
  const float emin = mn;
  const float inv_den = 1.f / (mx + 1e-6f);

  const float* xp = x + (size_t)bc * HW + 4 * lane;
  const float* ep = edge + (size_t)b * HW + 4 * lane;
  float* op = out + (size_t)bc * HW + 4 * lane;

  // Stage 1: hblur rows h0-3 .. h0+TH+2 into LDS (zero rows outside image).
  for (int r = wv; r < TH + 6; r += 4) {
    const int gh = h0 - 3 + r;
    float4 o = {0.f, 0.f, 0.f, 0.f};
    if (gh >= 0 && gh < H) {
      float4 v = ld4(xp + (size_t)gh * W);
      float4 ev = ld4(ep + (size_t)gh * W);
      float L1 = __shfl_up(v.y, 1), L2 = __shfl_up(v.z, 1), L3 = __shfl_up(v.w, 1);
      float R1 = __shfl_down(v.x, 1), R2 = __shfl_down(v.y, 1), R3 = __shfl_down(v.z, 1);
      if (lane == 0)  { L1 = 0.f; L2 = 0.f; L3 = 0.f; }
      if (lane == 63) { R1 = 0.f; R2 = 0.f; R3 = 0.f; }
      const float win[10] = {L1, L2, L3, v.x, v.y, v.z, v.w, R1, R2, R3};
      const float E[4] = {ev.x, ev.y, ev.z, ev.w};
      float acc[4];
      #pragma unroll
      for (int j = 0; j < 4; ++j) {
        float e1, iv;
        wt_px(E[j], emin, inv_den, e1, iv);
        acc[j] = blur7(win + j, e1, iv);
      }
      o.x = acc[0]; o.y = acc[1]; o.z = acc[2]; o.w = acc[3];
    }
    *(float4*)&hb[r][4 * lane] = o;
  }
  __syncthreads();

  // Stage 2: vblur. Wave wv owns output rows [wv*8, wv*8+8), rolling window.
  const int r0 = wv * 8;
  float win7[7][4];
  #pragma unroll
  for (int i = 0; i < 7; ++i) {
    float4 v = *(const float4*)&hb[r0 + i][4 * lane];
    win7[i][0] = v.x; win7[i][1] = v.y; win7[i][2] = v.z; win7[i][3] = v.w;
  }
  #pragma unroll
  for (int k = 0; k < 8; ++k) {
    const int gh = h0 + r0 + k;
    float4 ev = ld4(ep + (size_t)gh * W);
    const float E[4] = {ev.x, ev.y, ev.z, ev.w};
    float acc[4];
    #pragma unroll
    for (int j = 0; j < 4; ++j) {
      float e1, iv;
      wt_px(E[j], emin, inv_den, e1, iv);
      float col[7];
      #pragma unroll
      for (int i = 0; i < 7; ++i) col[i] = win7[i][j];
      acc[j] = blur7(col, e1, iv);
    }
    st4(op + (size_t)gh * W, acc[0], acc[1], acc[2], acc[3]);
    if (k < 7) {
      #pragma unroll
      for (int i = 0; i < 6; ++i) {
        #pragma unroll
        for (int j = 0; j < 4; ++j) win7[i][j] = win7[i + 1][j];
      }
      float4 nv = *(const float4*)&hb[r0 + k + 7][4 * lane];
      win7[6][0] = nv.x; win7[6][1] = nv.y; win7[6][2] = nv.z; win7[6][3] = nv.w;
    }
  }
}

extern "C" void kernel_launch(void* const* d_in, const int* in_sizes, int n_in,
                              void* d_out, int out_size, void* d_ws, size_t ws_size,
                              hipStream_t stream) {
  const float* x = (const float*)d_in[0];
  float* out = (float*)d_out;

  float* edge = (float*)d_ws;                                   // B*HW floats (1 MB)
  float* mmp = (float*)((char*)d_ws + (size_t)B * HW * 4);      // B*64*2 floats (2 KB)

  edge_kernel<<<B * (H / 4), 256, 0, stream>>>(x, edge, mmp);
  fusedblur_kernel<<<B * C * (H / TH), 256, 0, stream>>>(x, edge, mmp, out);
}